// Round 5
// baseline (870.143 us; speedup 1.0000x reference)
//
#include <hip/hip_runtime.h>

#define TSTEPS 30
#define KP2 136   // 128 h + 8 pad halfs -> 272B row stride (pads never read; kept for bank spread)

#define LOG2E     1.44269504f
#define TWO_LOG2E 2.88539008f

typedef _Float16 half8 __attribute__((ext_vector_type(8)));
typedef float f32x4 __attribute__((ext_vector_type(4)));

__device__ __forceinline__ float fexp2(float x) { return __builtin_amdgcn_exp2f(x); }
__device__ __forceinline__ float frcp(float x)  { return __builtin_amdgcn_rcpf(x); }
// pre-scaled forms: sigmoid arg pre-multiplied by log2e, tanh arg by 2*log2e
__device__ __forceinline__ float fsig_pre(float x)  { return frcp(1.0f + fexp2(-x)); }
__device__ __forceinline__ float ftanh_pre(float x) { return 1.0f - 2.0f * frcp(1.0f + fexp2(x)); }

// Block = 512 threads = 8 waves, 32 batch rows, 30 steps, ONE barrier per step.
// h double-buffered in LDS (hi/lo f16). x_t never crosses waves: every wave
// replicates the M-tile eacc MFMAs (M = W_sp@W_out, so x_t = tanh(M h_t + m0) for t>=1),
// tanh, round-trips through a wave-private LDS scratch (C->A layout), then feeds its
// own x-MFMA. At t==0 the scratch holds obs-derived x_0 (DO NOT clobber — R4 bug).
// Gate bias rides a 1.0 K-row (e=31) of the x scratch. rel output via Wout-tile
// eacc on waves 2/3 (stored with 1-step delay + tail).
__global__ __launch_bounds__(512, 2)
void lstm30_kernel(const float* __restrict__ last_obs_rel,
                   const float* __restrict__ h0,
                   const float* __restrict__ c0,
                   const float* __restrict__ W_sp,
                   const float* __restrict__ b_sp,
                   const float* __restrict__ W_ih,
                   const float* __restrict__ b_ih,
                   const float* __restrict__ W_hh,
                   const float* __restrict__ b_hh,
                   const float* __restrict__ W_out,
                   const float* __restrict__ b_out,
                   float* __restrict__ out)
{
    __shared__ _Float16 hA[2][32][KP2];       // h_hi double-buffered
    __shared__ _Float16 lA[2][32][KP2];       // h_lo double-buffered
    __shared__ _Float16 xS[8][2][16][32];     // wave-private x scratch: [w][tt][row][e]; e16..30=0, e31=1.0

    const int tid  = threadIdx.x;
    const int w    = tid >> 6;
    const int L    = tid & 63;
    const int quad = L >> 4;
    const int col  = L & 15;
    const int base = blockIdx.x << 5;

    // ---- gate B fragments: W'[k][G], G = nt*128 + 16w + col, pre-scaled; bias at W'-row 159 ----
    half8 Wf[4][5];
    #pragma unroll
    for (int nt = 0; nt < 4; ++nt) {
        const int G = nt * 128 + w * 16 + col;
        const float gsc = (nt == 2) ? TWO_LOG2E : LOG2E;
        #pragma unroll
        for (int kc = 0; kc < 5; ++kc) {
            const int k0 = kc * 32 + quad * 8;
            float v[8];
            if (k0 < 128) {
                const float4 a = *(const float4*)&W_hh[G * 128 + k0];
                const float4 b = *(const float4*)&W_hh[G * 128 + k0 + 4];
                v[0]=a.x; v[1]=a.y; v[2]=a.z; v[3]=a.w;
                v[4]=b.x; v[5]=b.y; v[6]=b.z; v[7]=b.w;
            } else if (k0 < 144) {
                const float4 a = *(const float4*)&W_ih[G * 16 + (k0 - 128)];
                const float4 b = *(const float4*)&W_ih[G * 16 + (k0 - 128) + 4];
                v[0]=a.x; v[1]=a.y; v[2]=a.z; v[3]=a.w;
                v[4]=b.x; v[5]=b.y; v[6]=b.z; v[7]=b.w;
            } else {
                #pragma unroll
                for (int jj = 0; jj < 8; ++jj) v[jj] = 0.0f;
                if (k0 + 7 == 159) v[7] = b_ih[G] + b_hh[G];   // bias K-row (pairs with xS e=31 == 1.0)
            }
            half8 hh;
            #pragma unroll
            for (int jj = 0; jj < 8; ++jj) hh[jj] = (_Float16)(v[jj] * gsc);
            Wf[nt][kc] = hh;
        }
    }

    // per-lane small constants
    const float ws0 = W_sp[col * 2 + 0];
    const float ws1 = W_sp[col * 2 + 1];
    const float bs  = b_sp[col];
    const float bo0 = b_out[0], bo1 = b_out[1];

    // ---- M-tile frags (ALL waves): M[e=col][k], pre-scaled 2log2e; Wout-tile frags (used by waves 2/3) ----
    half8 Mf[4], Ef2[4];
    #pragma unroll
    for (int kc = 0; kc < 4; ++kc) {
        const int k0 = kc * 32 + quad * 8;
        const float4 a0 = *(const float4*)&W_out[k0];
        const float4 a1 = *(const float4*)&W_out[k0 + 4];
        const float4 b0 = *(const float4*)&W_out[128 + k0];
        const float4 b1 = *(const float4*)&W_out[128 + k0 + 4];
        float r0[8] = {a0.x,a0.y,a0.z,a0.w,a1.x,a1.y,a1.z,a1.w};
        float r1[8] = {b0.x,b0.y,b0.z,b0.w,b1.x,b1.y,b1.z,b1.w};
        half8 hm, he;
        #pragma unroll
        for (int jj = 0; jj < 8; ++jj) {
            hm[jj] = (_Float16)((ws0 * r0[jj] + ws1 * r1[jj]) * TWO_LOG2E);
            he[jj] = (_Float16)((col == 0) ? r0[jj] : (col == 1) ? r1[jj] : 0.0f);
        }
        Mf[kc] = hm;
        Ef2[kc] = he;
    }
    const float einitM = (ws0 * bo0 + ws1 * bo1 + bs) * TWO_LOG2E;
    const float einitW = (col == 0) ? bo0 : (col == 1) ? bo1 : 0.0f;

    // c state: lane owns c[tile][r] for row = tile*16 + quad*4 + r, hidden = 16w+col
    float c[2][4];
    #pragma unroll
    for (int tt = 0; tt < 2; ++tt)
        #pragma unroll
        for (int r = 0; r < 4; ++r)
            c[tt][r] = c0[(base + tt * 16 + quad * 4 + r) * 128 + w * 16 + col];

    // h0 -> hi/lo split into buffer 0 (coalesced)
    for (int idx = tid; idx < 32 * 128; idx += 512) {
        const int r = idx >> 7, k = idx & 127;
        const float v = h0[base * 128 + idx];
        const _Float16 hi = (_Float16)v;
        hA[0][r][k] = hi;
        lA[0][r][k] = (_Float16)(v - (float)hi);
    }

    // xS init (wave-private): e<16 from obs; e in [16,31) zero; e==31 -> 1.0 (bias row)
    #pragma unroll
    for (int tt = 0; tt < 2; ++tt)
        #pragma unroll
        for (int r = 0; r < 4; ++r) {
            const int row = quad * 4 + r;
            const float p0 = last_obs_rel[(base + tt * 16 + row) * 2 + 0];
            const float p1 = last_obs_rel[(base + tt * 16 + row) * 2 + 1];
            xS[w][tt][row][col] = (_Float16)ftanh_pre(TWO_LOG2E * (ws0 * p0 + ws1 * p1 + bs));
        }
    for (int flat = L; flat < 2 * 16 * 16; flat += 64) {
        const int tt = flat >> 8, row = (flat >> 4) & 15, e2 = 16 + (flat & 15);
        xS[w][tt][row][e2] = (_Float16)((e2 == 31) ? 1.0f : 0.0f);
    }

    __syncthreads();

    const int j = w * 16 + col;
    const bool w23 = (w == 2 || w == 3);

    for (int t = 0; t < TSTEPS; ++t) {
        const int p = t & 1;

        f32x4 acc[2][4];
        f32x4 eaccM[2];
        f32x4 eaccW;
        #pragma unroll
        for (int tt = 0; tt < 2; ++tt) {
            #pragma unroll
            for (int nt = 0; nt < 4; ++nt) {
                f32x4 z = {0.0f, 0.0f, 0.0f, 0.0f};
                acc[tt][nt] = z;
            }
            f32x4 em = {einitM, einitM, einitM, einitM};
            eaccM[tt] = em;
        }
        { f32x4 ew = {einitW, einitW, einitW, einitW}; eaccW = ew; }

        // ---- K=128 (h) MFMAs: gates + replicated M-eacc (+ Wout-eacc on waves 2/3) ----
        #pragma unroll
        for (int tt = 0; tt < 2; ++tt) {
            const int arow = tt * 16 + col;
            half8 aH[4];
            #pragma unroll
            for (int kc = 0; kc < 4; ++kc)
                aH[kc] = *(const half8*)&hA[p][arow][kc * 32 + quad * 8];
            #pragma unroll
            for (int kc = 0; kc < 4; ++kc) {
                #pragma unroll
                for (int nt = 0; nt < 4; ++nt)
                    acc[tt][nt] = __builtin_amdgcn_mfma_f32_16x16x32_f16(aH[kc], Wf[nt][kc], acc[tt][nt], 0, 0, 0);
                eaccM[tt] = __builtin_amdgcn_mfma_f32_16x16x32_f16(aH[kc], Mf[kc], eaccM[tt], 0, 0, 0);
            }
            if (w23 && (w & 1) == tt) {
                #pragma unroll
                for (int kc = 0; kc < 4; ++kc)
                    eaccW = __builtin_amdgcn_mfma_f32_16x16x32_f16(aH[kc], Ef2[kc], eaccW, 0, 0, 0);
            }
            half8 aL[4];
            #pragma unroll
            for (int kc = 0; kc < 4; ++kc)
                aL[kc] = *(const half8*)&lA[p][arow][kc * 32 + quad * 8];
            #pragma unroll
            for (int kc = 0; kc < 4; ++kc) {
                #pragma unroll
                for (int nt = 0; nt < 4; ++nt)
                    acc[tt][nt] = __builtin_amdgcn_mfma_f32_16x16x32_f16(aL[kc], Wf[nt][kc], acc[tt][nt], 0, 0, 0);
                eaccM[tt] = __builtin_amdgcn_mfma_f32_16x16x32_f16(aL[kc], Mf[kc], eaccM[tt], 0, 0, 0);
            }
            if (w23 && (w & 1) == tt) {
                #pragma unroll
                for (int kc = 0; kc < 4; ++kc)
                    eaccW = __builtin_amdgcn_mfma_f32_16x16x32_f16(aL[kc], Ef2[kc], eaccW, 0, 0, 0);
            }
        }

        // ---- x_t = tanh(xpre): write wave-private scratch (C-layout), no barrier.
        //      t==0 MUST keep the obs-derived x_0 from init (R4 bug was clobbering it). ----
        if (t > 0) {
            #pragma unroll
            for (int tt = 0; tt < 2; ++tt)
                #pragma unroll
                for (int r = 0; r < 4; ++r)
                    xS[w][tt][quad * 4 + r][col] = (_Float16)ftanh_pre(eaccM[tt][r]);
        }

        // ---- rel_{t-1} store (waves 2/3) ----
        if (w23 && t > 0 && col < 2) {
            const int tt = w & 1;
            #pragma unroll
            for (int r = 0; r < 4; ++r) {
                const int row = base + tt * 16 + quad * 4 + r;
                out[row * (TSTEPS * 2) + (t - 1) * 2 + col] = eaccW[r];
            }
        }

        // ---- x-MFMA (A-layout read of own scratch; e=31 row carries gate bias) ----
        #pragma unroll
        for (int tt = 0; tt < 2; ++tt) {
            const half8 xa = *(const half8*)&xS[w][tt][col][quad * 8];
            #pragma unroll
            for (int nt = 0; nt < 4; ++nt)
                acc[tt][nt] = __builtin_amdgcn_mfma_f32_16x16x32_f16(xa, Wf[nt][4], acc[tt][nt], 0, 0, 0);
        }

        // ---- cell -> h_{t+1} into the OTHER buffer ----
        #pragma unroll
        for (int tt = 0; tt < 2; ++tt)
            #pragma unroll
            for (int r = 0; r < 4; ++r) {
                const int row = tt * 16 + quad * 4 + r;
                const float gi = fsig_pre(acc[tt][0][r]);
                const float gf = fsig_pre(acc[tt][1][r]);
                const float gg = ftanh_pre(acc[tt][2][r]);
                const float go = fsig_pre(acc[tt][3][r]);
                c[tt][r] = gf * c[tt][r] + gi * gg;
                const float h = go * ftanh_pre(TWO_LOG2E * c[tt][r]);
                const _Float16 hi = (_Float16)h;
                hA[p ^ 1][row][j] = hi;
                lA[p ^ 1][row][j] = (_Float16)(h - (float)hi);
            }

        __syncthreads();   // h_{t+1} visible; also protects buffer reuse two steps out
    }

    // ---- tail: rel_{29} from h_30 (in buffer TSTEPS&1 == 0), waves 2/3 ----
    if (w23) {
        const int tt = w & 1;
        f32x4 eaccW;
        { f32x4 ew = {einitW, einitW, einitW, einitW}; eaccW = ew; }
        const int arow = tt * 16 + col;
        #pragma unroll
        for (int kc = 0; kc < 4; ++kc) {
            const half8 aH = *(const half8*)&hA[0][arow][kc * 32 + quad * 8];
            eaccW = __builtin_amdgcn_mfma_f32_16x16x32_f16(aH, Ef2[kc], eaccW, 0, 0, 0);
        }
        #pragma unroll
        for (int kc = 0; kc < 4; ++kc) {
            const half8 aL = *(const half8*)&lA[0][arow][kc * 32 + quad * 8];
            eaccW = __builtin_amdgcn_mfma_f32_16x16x32_f16(aL, Ef2[kc], eaccW, 0, 0, 0);
        }
        if (col < 2) {
            #pragma unroll
            for (int r = 0; r < 4; ++r) {
                const int row = base + tt * 16 + quad * 4 + r;
                out[row * (TSTEPS * 2) + (TSTEPS - 1) * 2 + col] = eaccW[r];
            }
        }
    }
}

extern "C" void kernel_launch(void* const* d_in, const int* in_sizes, int n_in,
                              void* d_out, int out_size, void* d_ws, size_t ws_size,
                              hipStream_t stream) {
    const float* last_obs_rel = (const float*)d_in[1];
    const float* h0    = (const float*)d_in[2];
    const float* c0    = (const float*)d_in[3];
    const float* W_sp  = (const float*)d_in[4];
    const float* b_sp  = (const float*)d_in[5];
    const float* W_ih  = (const float*)d_in[6];
    const float* b_ih  = (const float*)d_in[7];
    const float* W_hh  = (const float*)d_in[8];
    const float* b_hh  = (const float*)d_in[9];
    const float* W_out = (const float*)d_in[10];
    const float* b_out = (const float*)d_in[11];
    float* out = (float*)d_out;

    const int batch = in_sizes[2] / 128;   // 65536
    lstm30_kernel<<<dim3(batch / 32), dim3(512), 0, stream>>>(
        last_obs_rel, h0, c0, W_sp, b_sp, W_ih, b_ih, W_hh, b_hh, W_out, b_out, out);
}

// Round 6
// 850.209 us; speedup vs baseline: 1.0234x; 1.0234x over previous
//
#include <hip/hip_runtime.h>

#define TSTEPS 30
#define KP2 136   // 128 h + 8 pad halfs; gate frags read only k<128 (pads never touched)

#define LOG2E     1.44269504f
#define TWO_LOG2E 2.88539008f

typedef _Float16 half8 __attribute__((ext_vector_type(8)));
typedef float f32x4 __attribute__((ext_vector_type(4)));

__device__ __forceinline__ float fexp2(float x) { return __builtin_amdgcn_exp2f(x); }
__device__ __forceinline__ float frcp(float x)  { return __builtin_amdgcn_rcpf(x); }
// pre-scaled forms: sigmoid arg pre-multiplied by log2e, tanh arg by 2*log2e
__device__ __forceinline__ float fsig_pre(float x)  { return frcp(1.0f + fexp2(-x)); }
__device__ __forceinline__ float ftanh_pre(float x) { return 1.0f - 2.0f * frcp(1.0f + fexp2(x)); }

// Block = 512 threads = 8 waves, 32 batch rows as TWO independent 16-row tiles (A=0..15, B=16..31)
// software-pipelined half a step apart. Each barrier interval holds one tile's h-MFMA stream
// AND the other tile's x-MFMA + cell VALU -> in-wave MFMA/VALU dual-pipe overlap.
//   even phase (step k): h-MFMA(A,k) [+ wave0 eaccM(A), wave2 eaccW(A)] ; x-MFMA(B,k-1)+cell(B,k-1)
//   odd  phase (step k): h-MFMA(B,k) [+ wave1 eaccM(B), wave3 eaccW(B)] ; x-MFMA(A,k)+cell(A,k)
// x_t = tanh(M h_t + m0), M = W_sp@W_out (x never needs the obs path after t=0).
// rel_{k-1} = W_out h_k + b_out rides the h-MFMA phase via eaccW. Guards: xS/rel only for k>0.
__global__ __launch_bounds__(512, 2)
void lstm30_kernel(const float* __restrict__ last_obs_rel,
                   const float* __restrict__ h0,
                   const float* __restrict__ c0,
                   const float* __restrict__ W_sp,
                   const float* __restrict__ b_sp,
                   const float* __restrict__ W_ih,
                   const float* __restrict__ b_ih,
                   const float* __restrict__ W_hh,
                   const float* __restrict__ b_hh,
                   const float* __restrict__ W_out,
                   const float* __restrict__ b_out,
                   float* __restrict__ out)
{
    __shared__ _Float16 hA[32][KP2];      // h_hi
    __shared__ _Float16 lA[32][KP2];      // h_lo
    __shared__ _Float16 xS[2][16][32];    // x per tile: e0..15 = tanh vals, e16..31 = 0 (zeroed once)

    const int tid  = threadIdx.x;
    const int w    = tid >> 6;
    const int L    = tid & 63;
    const int quad = L >> 4;
    const int col  = L & 15;
    const int base = blockIdx.x << 5;

    // ---- gate B fragments: W'[k][G], G = nt*128 + 16w + col, pre-scaled; bias separate ----
    half8 Wf[4][5];
    float bias[4];
    #pragma unroll
    for (int nt = 0; nt < 4; ++nt) {
        const int G = nt * 128 + w * 16 + col;
        const float gsc = (nt == 2) ? TWO_LOG2E : LOG2E;
        bias[nt] = (b_ih[G] + b_hh[G]) * gsc;
        #pragma unroll
        for (int kc = 0; kc < 5; ++kc) {
            const int k0 = kc * 32 + quad * 8;
            float v[8];
            if (k0 < 128) {
                const float4 a = *(const float4*)&W_hh[G * 128 + k0];
                const float4 b = *(const float4*)&W_hh[G * 128 + k0 + 4];
                v[0]=a.x; v[1]=a.y; v[2]=a.z; v[3]=a.w;
                v[4]=b.x; v[5]=b.y; v[6]=b.z; v[7]=b.w;
            } else if (k0 < 144) {
                const float4 a = *(const float4*)&W_ih[G * 16 + (k0 - 128)];
                const float4 b = *(const float4*)&W_ih[G * 16 + (k0 - 128) + 4];
                v[0]=a.x; v[1]=a.y; v[2]=a.z; v[3]=a.w;
                v[4]=b.x; v[5]=b.y; v[6]=b.z; v[7]=b.w;
            } else {
                #pragma unroll
                for (int jj = 0; jj < 8; ++jj) v[jj] = 0.0f;
            }
            half8 hh;
            #pragma unroll
            for (int jj = 0; jj < 8; ++jj) hh[jj] = (_Float16)(v[jj] * gsc);
            Wf[nt][kc] = hh;
        }
    }

    const float ws0 = W_sp[col * 2 + 0];
    const float ws1 = W_sp[col * 2 + 1];
    const float bs  = b_sp[col];
    const float bo0 = b_out[0], bo1 = b_out[1];

    // ---- M-tile frags (used by waves 0/1) and Wout-tile frags (waves 2/3) ----
    half8 Mf[4], Ef2[4];
    #pragma unroll
    for (int kc = 0; kc < 4; ++kc) {
        const int k0 = kc * 32 + quad * 8;
        const float4 a0 = *(const float4*)&W_out[k0];
        const float4 a1 = *(const float4*)&W_out[k0 + 4];
        const float4 b0 = *(const float4*)&W_out[128 + k0];
        const float4 b1 = *(const float4*)&W_out[128 + k0 + 4];
        float r0[8] = {a0.x,a0.y,a0.z,a0.w,a1.x,a1.y,a1.z,a1.w};
        float r1[8] = {b0.x,b0.y,b0.z,b0.w,b1.x,b1.y,b1.z,b1.w};
        half8 hm, he;
        #pragma unroll
        for (int jj = 0; jj < 8; ++jj) {
            hm[jj] = (_Float16)((ws0 * r0[jj] + ws1 * r1[jj]) * TWO_LOG2E);
            he[jj] = (_Float16)((col == 0) ? r0[jj] : (col == 1) ? r1[jj] : 0.0f);
        }
        Mf[kc] = hm;
        Ef2[kc] = he;
    }
    const float einitM = (ws0 * bo0 + ws1 * bo1 + bs) * TWO_LOG2E;
    const float einitW = (col == 0) ? bo0 : (col == 1) ? bo1 : 0.0f;

    // c state: c[tile][r], row = tile*16 + quad*4 + r, hidden j = 16w+col
    float c[2][4];
    #pragma unroll
    for (int tt = 0; tt < 2; ++tt)
        #pragma unroll
        for (int r = 0; r < 4; ++r)
            c[tt][r] = c0[(base + tt * 16 + quad * 4 + r) * 128 + w * 16 + col];

    // ---- prologue: h0 split (pads never read -> no zero-fill), x0 per tile, xS tail zeros ----
    for (int idx = tid; idx < 32 * 128; idx += 512) {
        const int r = idx >> 7, k = idx & 127;
        const float v = h0[base * 128 + idx];
        const _Float16 hi = (_Float16)v;
        hA[r][k] = hi;
        lA[r][k] = (_Float16)(v - (float)hi);
    }
    {
        const int rr = tid >> 4;              // 0..31
        const float p0 = last_obs_rel[(base + rr) * 2 + 0];
        const float p1 = last_obs_rel[(base + rr) * 2 + 1];
        xS[rr >> 4][rr & 15][col] = (_Float16)ftanh_pre(TWO_LOG2E * (ws0 * p0 + ws1 * p1 + bs));
    }
    for (int flat = tid; flat < 2 * 16 * 16; flat += 512) {
        const int T = flat >> 8, row = (flat >> 4) & 15;
        xS[T][row][16 + (flat & 15)] = (_Float16)0.0f;
    }
    __syncthreads();

    const int j = w * 16 + col;

    f32x4 accA[4], accB[4];

    for (int k = 0; k < TSTEPS; ++k) {
        // ================= EVEN phase: tile A step k; finishes tile B step k-1 =================
        {
            half8 aH[4];
            #pragma unroll
            for (int kc = 0; kc < 4; ++kc)
                aH[kc] = *(const half8*)&hA[col][kc * 32 + quad * 8];

            if (k > 0) {   // finish gates(B,k-1) with the x part
                const half8 xb = *(const half8*)&xS[1][col][quad * 8];
                #pragma unroll
                for (int nt = 0; nt < 4; ++nt)
                    accB[nt] = __builtin_amdgcn_mfma_f32_16x16x32_f16(xb, Wf[nt][4], accB[nt], 0, 0, 0);
            }

            #pragma unroll
            for (int nt = 0; nt < 4; ++nt) {
                f32x4 bv = {bias[nt], bias[nt], bias[nt], bias[nt]};
                accA[nt] = bv;
            }
            f32x4 eM = {einitM, einitM, einitM, einitM};
            f32x4 eW = {einitW, einitW, einitW, einitW};

            #pragma unroll
            for (int kc = 0; kc < 4; ++kc) {
                #pragma unroll
                for (int nt = 0; nt < 4; ++nt)
                    accA[nt] = __builtin_amdgcn_mfma_f32_16x16x32_f16(aH[kc], Wf[nt][kc], accA[nt], 0, 0, 0);
                if (w == 0) eM = __builtin_amdgcn_mfma_f32_16x16x32_f16(aH[kc], Mf[kc],  eM, 0, 0, 0);
                if (w == 2) eW = __builtin_amdgcn_mfma_f32_16x16x32_f16(aH[kc], Ef2[kc], eW, 0, 0, 0);
            }
            half8 aL[4];
            #pragma unroll
            for (int kc = 0; kc < 4; ++kc)
                aL[kc] = *(const half8*)&lA[col][kc * 32 + quad * 8];
            #pragma unroll
            for (int kc = 0; kc < 4; ++kc) {
                #pragma unroll
                for (int nt = 0; nt < 4; ++nt)
                    accA[nt] = __builtin_amdgcn_mfma_f32_16x16x32_f16(aL[kc], Wf[nt][kc], accA[nt], 0, 0, 0);
                if (w == 0) eM = __builtin_amdgcn_mfma_f32_16x16x32_f16(aL[kc], Mf[kc],  eM, 0, 0, 0);
                if (w == 2) eW = __builtin_amdgcn_mfma_f32_16x16x32_f16(aL[kc], Ef2[kc], eW, 0, 0, 0);
            }

            if (k > 0) {   // cell(B, k-1) -> h_k(B)
                #pragma unroll
                for (int r = 0; r < 4; ++r) {
                    const int row = 16 + quad * 4 + r;
                    const float gi = fsig_pre(accB[0][r]);
                    const float gf = fsig_pre(accB[1][r]);
                    const float gg = ftanh_pre(accB[2][r]);
                    const float go = fsig_pre(accB[3][r]);
                    c[1][r] = gf * c[1][r] + gi * gg;
                    const float h = go * ftanh_pre(TWO_LOG2E * c[1][r]);
                    const _Float16 hi = (_Float16)h;
                    hA[row][j] = hi;
                    lA[row][j] = (_Float16)(h - (float)hi);
                }
            }
            if (k > 0 && w == 0) {   // x_k(A) (k=0 keeps obs-x0: R4 lesson)
                #pragma unroll
                for (int r = 0; r < 4; ++r)
                    xS[0][quad * 4 + r][col] = (_Float16)ftanh_pre(eM[r]);
            }
            if (k > 0 && w == 2 && col < 2) {   // rel_{k-1}(A)
                #pragma unroll
                for (int r = 0; r < 4; ++r)
                    out[(base + quad * 4 + r) * (TSTEPS * 2) + (k - 1) * 2 + col] = eW[r];
            }
            __syncthreads();
        }
        // ================= ODD phase: tile B step k; finishes tile A step k =================
        {
            half8 aH[4];
            #pragma unroll
            for (int kc = 0; kc < 4; ++kc)
                aH[kc] = *(const half8*)&hA[16 + col][kc * 32 + quad * 8];

            {   // finish gates(A,k) with the x part (xS[0] = x_k(A): obs at k=0, else written even phase)
                const half8 xa = *(const half8*)&xS[0][col][quad * 8];
                #pragma unroll
                for (int nt = 0; nt < 4; ++nt)
                    accA[nt] = __builtin_amdgcn_mfma_f32_16x16x32_f16(xa, Wf[nt][4], accA[nt], 0, 0, 0);
            }

            #pragma unroll
            for (int nt = 0; nt < 4; ++nt) {
                f32x4 bv = {bias[nt], bias[nt], bias[nt], bias[nt]};
                accB[nt] = bv;
            }
            f32x4 eM = {einitM, einitM, einitM, einitM};
            f32x4 eW = {einitW, einitW, einitW, einitW};

            #pragma unroll
            for (int kc = 0; kc < 4; ++kc) {
                #pragma unroll
                for (int nt = 0; nt < 4; ++nt)
                    accB[nt] = __builtin_amdgcn_mfma_f32_16x16x32_f16(aH[kc], Wf[nt][kc], accB[nt], 0, 0, 0);
                if (w == 1) eM = __builtin_amdgcn_mfma_f32_16x16x32_f16(aH[kc], Mf[kc],  eM, 0, 0, 0);
                if (w == 3) eW = __builtin_amdgcn_mfma_f32_16x16x32_f16(aH[kc], Ef2[kc], eW, 0, 0, 0);
            }
            half8 aL[4];
            #pragma unroll
            for (int kc = 0; kc < 4; ++kc)
                aL[kc] = *(const half8*)&lA[16 + col][kc * 32 + quad * 8];
            #pragma unroll
            for (int kc = 0; kc < 4; ++kc) {
                #pragma unroll
                for (int nt = 0; nt < 4; ++nt)
                    accB[nt] = __builtin_amdgcn_mfma_f32_16x16x32_f16(aL[kc], Wf[nt][kc], accB[nt], 0, 0, 0);
                if (w == 1) eM = __builtin_amdgcn_mfma_f32_16x16x32_f16(aL[kc], Mf[kc],  eM, 0, 0, 0);
                if (w == 3) eW = __builtin_amdgcn_mfma_f32_16x16x32_f16(aL[kc], Ef2[kc], eW, 0, 0, 0);
            }

            {   // cell(A, k) -> h_{k+1}(A)
                #pragma unroll
                for (int r = 0; r < 4; ++r) {
                    const int row = quad * 4 + r;
                    const float gi = fsig_pre(accA[0][r]);
                    const float gf = fsig_pre(accA[1][r]);
                    const float gg = ftanh_pre(accA[2][r]);
                    const float go = fsig_pre(accA[3][r]);
                    c[0][r] = gf * c[0][r] + gi * gg;
                    const float h = go * ftanh_pre(TWO_LOG2E * c[0][r]);
                    const _Float16 hi = (_Float16)h;
                    hA[row][j] = hi;
                    lA[row][j] = (_Float16)(h - (float)hi);
                }
            }
            if (k > 0 && w == 1) {   // x_k(B) (k=0 keeps obs-x0)
                #pragma unroll
                for (int r = 0; r < 4; ++r)
                    xS[1][quad * 4 + r][col] = (_Float16)ftanh_pre(eM[r]);
            }
            if (k > 0 && w == 3 && col < 2) {   // rel_{k-1}(B)
                #pragma unroll
                for (int r = 0; r < 4; ++r)
                    out[(base + 16 + quad * 4 + r) * (TSTEPS * 2) + (k - 1) * 2 + col] = eW[r];
            }
            __syncthreads();
        }
    }

    // ================= epilogue: finish tile B step 29; rel_29 for both tiles =================
    {
        {   // x part of gates(B,29): xS[1] = x_29(B), written in odd phase k=29
            const half8 xb = *(const half8*)&xS[1][col][quad * 8];
            #pragma unroll
            for (int nt = 0; nt < 4; ++nt)
                accB[nt] = __builtin_amdgcn_mfma_f32_16x16x32_f16(xb, Wf[nt][4], accB[nt], 0, 0, 0);
        }
        // rel_29(A) = W_out h_30(A) (rows 0..15, written odd k=29) — concurrent with cell(B,29)
        if (w == 2) {
            f32x4 eW = {einitW, einitW, einitW, einitW};
            #pragma unroll
            for (int kc = 0; kc < 4; ++kc) {
                const half8 aH = *(const half8*)&hA[col][kc * 32 + quad * 8];
                eW = __builtin_amdgcn_mfma_f32_16x16x32_f16(aH, Ef2[kc], eW, 0, 0, 0);
            }
            #pragma unroll
            for (int kc = 0; kc < 4; ++kc) {
                const half8 aL = *(const half8*)&lA[col][kc * 32 + quad * 8];
                eW = __builtin_amdgcn_mfma_f32_16x16x32_f16(aL, Ef2[kc], eW, 0, 0, 0);
            }
            if (col < 2) {
                #pragma unroll
                for (int r = 0; r < 4; ++r)
                    out[(base + quad * 4 + r) * (TSTEPS * 2) + (TSTEPS - 1) * 2 + col] = eW[r];
            }
        }
        // cell(B,29) -> h_30(B)
        #pragma unroll
        for (int r = 0; r < 4; ++r) {
            const int row = 16 + quad * 4 + r;
            const float gi = fsig_pre(accB[0][r]);
            const float gf = fsig_pre(accB[1][r]);
            const float gg = ftanh_pre(accB[2][r]);
            const float go = fsig_pre(accB[3][r]);
            c[1][r] = gf * c[1][r] + gi * gg;
            const float h = go * ftanh_pre(TWO_LOG2E * c[1][r]);
            const _Float16 hi = (_Float16)h;
            hA[row][j] = hi;
            lA[row][j] = (_Float16)(h - (float)hi);
        }
        __syncthreads();
        // rel_29(B) = W_out h_30(B)
        if (w == 3) {
            f32x4 eW = {einitW, einitW, einitW, einitW};
            #pragma unroll
            for (int kc = 0; kc < 4; ++kc) {
                const half8 aH = *(const half8*)&hA[16 + col][kc * 32 + quad * 8];
                eW = __builtin_amdgcn_mfma_f32_16x16x32_f16(aH, Ef2[kc], eW, 0, 0, 0);
            }
            #pragma unroll
            for (int kc = 0; kc < 4; ++kc) {
                const half8 aL = *(const half8*)&lA[16 + col][kc * 32 + quad * 8];
                eW = __builtin_amdgcn_mfma_f32_16x16x32_f16(aL, Ef2[kc], eW, 0, 0, 0);
            }
            if (col < 2) {
                #pragma unroll
                for (int r = 0; r < 4; ++r)
                    out[(base + 16 + quad * 4 + r) * (TSTEPS * 2) + (TSTEPS - 1) * 2 + col] = eW[r];
            }
        }
    }
}

extern "C" void kernel_launch(void* const* d_in, const int* in_sizes, int n_in,
                              void* d_out, int out_size, void* d_ws, size_t ws_size,
                              hipStream_t stream) {
    const float* last_obs_rel = (const float*)d_in[1];
    const float* h0    = (const float*)d_in[2];
    const float* c0    = (const float*)d_in[3];
    const float* W_sp  = (const float*)d_in[4];
    const float* b_sp  = (const float*)d_in[5];
    const float* W_ih  = (const float*)d_in[6];
    const float* b_ih  = (const float*)d_in[7];
    const float* W_hh  = (const float*)d_in[8];
    const float* b_hh  = (const float*)d_in[9];
    const float* W_out = (const float*)d_in[10];
    const float* b_out = (const float*)d_in[11];
    float* out = (float*)d_out;

    const int batch = in_sizes[2] / 128;   // 65536
    lstm30_kernel<<<dim3(batch / 32), dim3(512), 0, stream>>>(
        last_obs_rel, h0, c0, W_sp, b_sp, W_ih, b_ih, W_hh, b_hh, W_out, b_out, out);
}

// Round 7
// 734.237 us; speedup vs baseline: 1.1851x; 1.1579x over previous
//
#include <hip/hip_runtime.h>

#define TSTEPS 30
#define KP2 136   // 128 h + 8 pad halfs; gate frags read only k<128

#define LOG2E     1.44269504f
#define TWO_LOG2E 2.88539008f

typedef _Float16 half8 __attribute__((ext_vector_type(8)));
typedef float f32x4 __attribute__((ext_vector_type(4)));

__device__ __forceinline__ float fexp2(float x) { return __builtin_amdgcn_exp2f(x); }
__device__ __forceinline__ float frcp(float x)  { return __builtin_amdgcn_rcpf(x); }
__device__ __forceinline__ float fsig_pre(float x)  { return frcp(1.0f + fexp2(-x)); }
__device__ __forceinline__ float ftanh_pre(float x) { return 1.0f - 2.0f * frcp(1.0f + fexp2(x)); }

// Block = 8 waves, 32 rows as two pipelined 16-row tiles (A=0..15, B=16..31), 2 barriers/step.
//   even phase (k): gates-MFMA(A,k) ; x-MFMA(B)+cell(B,k-1) interleaved between MFMA passes
//   odd  phase (k): gates-MFMA(B,k) ; x-MFMA(A)+cell(A,k)
// Register diet vs R6 (spill fix): ONE Ef[4]/einit per wave (M-cols on w0/w1, Wout-cols on
// w2/w3), ONE phase-local eacc, hi/lo frags share one register array.
__global__ __launch_bounds__(512, 2)
void lstm30_kernel(const float* __restrict__ last_obs_rel,
                   const float* __restrict__ h0,
                   const float* __restrict__ c0,
                   const float* __restrict__ W_sp,
                   const float* __restrict__ b_sp,
                   const float* __restrict__ W_ih,
                   const float* __restrict__ b_ih,
                   const float* __restrict__ W_hh,
                   const float* __restrict__ b_hh,
                   const float* __restrict__ W_out,
                   const float* __restrict__ b_out,
                   float* __restrict__ out)
{
    __shared__ _Float16 hA[32][KP2];
    __shared__ _Float16 lA[32][KP2];
    __shared__ _Float16 xS[2][16][32];   // x per tile: e0..15 = x vals, e16..31 = 0

    const int tid  = threadIdx.x;
    const int w    = tid >> 6;
    const int L    = tid & 63;
    const int quad = L >> 4;
    const int col  = L & 15;
    const int base = blockIdx.x << 5;

    // ---- gate B fragments: W'[k][G], G = nt*128 + 16w + col, pre-scaled ----
    half8 Wf[4][5];
    float bias[4];
    #pragma unroll
    for (int nt = 0; nt < 4; ++nt) {
        const int G = nt * 128 + w * 16 + col;
        const float gsc = (nt == 2) ? TWO_LOG2E : LOG2E;
        bias[nt] = (b_ih[G] + b_hh[G]) * gsc;
        #pragma unroll
        for (int kc = 0; kc < 5; ++kc) {
            const int k0 = kc * 32 + quad * 8;
            float v[8];
            if (k0 < 128) {
                const float4 a = *(const float4*)&W_hh[G * 128 + k0];
                const float4 b = *(const float4*)&W_hh[G * 128 + k0 + 4];
                v[0]=a.x; v[1]=a.y; v[2]=a.z; v[3]=a.w;
                v[4]=b.x; v[5]=b.y; v[6]=b.z; v[7]=b.w;
            } else if (k0 < 144) {
                const float4 a = *(const float4*)&W_ih[G * 16 + (k0 - 128)];
                const float4 b = *(const float4*)&W_ih[G * 16 + (k0 - 128) + 4];
                v[0]=a.x; v[1]=a.y; v[2]=a.z; v[3]=a.w;
                v[4]=b.x; v[5]=b.y; v[6]=b.z; v[7]=b.w;
            } else {
                #pragma unroll
                for (int jj = 0; jj < 8; ++jj) v[jj] = 0.0f;
            }
            half8 hh;
            #pragma unroll
            for (int jj = 0; jj < 8; ++jj) hh[jj] = (_Float16)(v[jj] * gsc);
            Wf[nt][kc] = hh;
        }
    }

    const float ws0 = W_sp[col * 2 + 0];
    const float ws1 = W_sp[col * 2 + 1];
    const float bs  = b_sp[col];
    const float bo0 = b_out[0], bo1 = b_out[1];

    // ---- ONE extra-column fragment set per wave: M-cols (w0/w1) or Wout-cols (w2/w3) ----
    half8 Ef[4];
    float einit = 0.0f;
    if (w < 4) {
        const bool isM = (w < 2);
        #pragma unroll
        for (int kc = 0; kc < 4; ++kc) {
            const int k0 = kc * 32 + quad * 8;
            const float4 a0 = *(const float4*)&W_out[k0];
            const float4 a1 = *(const float4*)&W_out[k0 + 4];
            const float4 b0 = *(const float4*)&W_out[128 + k0];
            const float4 b1 = *(const float4*)&W_out[128 + k0 + 4];
            float r0[8] = {a0.x,a0.y,a0.z,a0.w,a1.x,a1.y,a1.z,a1.w};
            float r1[8] = {b0.x,b0.y,b0.z,b0.w,b1.x,b1.y,b1.z,b1.w};
            half8 he;
            #pragma unroll
            for (int jj = 0; jj < 8; ++jj)
                he[jj] = isM ? (_Float16)((ws0 * r0[jj] + ws1 * r1[jj]) * TWO_LOG2E)
                             : (_Float16)((col == 0) ? r0[jj] : (col == 1) ? r1[jj] : 0.0f);
            Ef[kc] = he;
        }
        einit = isM ? (ws0 * bo0 + ws1 * bo1 + bs) * TWO_LOG2E
                    : ((col == 0) ? bo0 : (col == 1) ? bo1 : 0.0f);
    }

    float c[2][4];
    #pragma unroll
    for (int tt = 0; tt < 2; ++tt)
        #pragma unroll
        for (int r = 0; r < 4; ++r)
            c[tt][r] = c0[(base + tt * 16 + quad * 4 + r) * 128 + w * 16 + col];

    // ---- prologue ----
    for (int idx = tid; idx < 32 * 128; idx += 512) {
        const int r = idx >> 7, k = idx & 127;
        const float v = h0[base * 128 + idx];
        const _Float16 hi = (_Float16)v;
        hA[r][k] = hi;
        lA[r][k] = (_Float16)(v - (float)hi);
    }
    {
        const int rr = tid >> 4;
        const float p0 = last_obs_rel[(base + rr) * 2 + 0];
        const float p1 = last_obs_rel[(base + rr) * 2 + 1];
        xS[rr >> 4][rr & 15][col] = (_Float16)ftanh_pre(TWO_LOG2E * (ws0 * p0 + ws1 * p1 + bs));
    }
    for (int flat = tid; flat < 2 * 16 * 16; flat += 512) {
        const int T = flat >> 8, row = (flat >> 4) & 15;
        xS[T][row][16 + (flat & 15)] = (_Float16)0.0f;
    }
    __syncthreads();

    const int j = w * 16 + col;
    f32x4 accA[4], accB[4];

    for (int k = 0; k < TSTEPS; ++k) {
        // ================= EVEN: gates(A,k) ; x+cell(B,k-1) =================
        {
            half8 a[4];
            #pragma unroll
            for (int kc = 0; kc < 4; ++kc)
                a[kc] = *(const half8*)&hA[col][kc * 32 + quad * 8];

            if (k > 0) {   // finish gates(B,k-1): x part
                const half8 xb = *(const half8*)&xS[1][col][quad * 8];
                #pragma unroll
                for (int nt = 0; nt < 4; ++nt)
                    accB[nt] = __builtin_amdgcn_mfma_f32_16x16x32_f16(xb, Wf[nt][4], accB[nt], 0, 0, 0);
            }

            #pragma unroll
            for (int nt = 0; nt < 4; ++nt) {
                f32x4 bv = {bias[nt], bias[nt], bias[nt], bias[nt]};
                accA[nt] = bv;
            }
            f32x4 eacc = {einit, einit, einit, einit};

            #pragma unroll
            for (int kc = 0; kc < 4; ++kc)
                #pragma unroll
                for (int nt = 0; nt < 4; ++nt)
                    accA[nt] = __builtin_amdgcn_mfma_f32_16x16x32_f16(a[kc], Wf[nt][kc], accA[nt], 0, 0, 0);
            if (k > 0 && (w == 0 || w == 2)) {
                #pragma unroll
                for (int kc = 0; kc < 4; ++kc)
                    eacc = __builtin_amdgcn_mfma_f32_16x16x32_f16(a[kc], Ef[kc], eacc, 0, 0, 0);
            }

            if (k > 0) {   // cell(B,k-1) rows 0-1 — VALU overlaps MFMA drain
                #pragma unroll
                for (int r = 0; r < 2; ++r) {
                    const int row = 16 + quad * 4 + r;
                    const float gi = fsig_pre(accB[0][r]);
                    const float gf = fsig_pre(accB[1][r]);
                    const float gg = ftanh_pre(accB[2][r]);
                    const float go = fsig_pre(accB[3][r]);
                    c[1][r] = gf * c[1][r] + gi * gg;
                    const float h = go * ftanh_pre(TWO_LOG2E * c[1][r]);
                    const _Float16 hi = (_Float16)h;
                    hA[row][j] = hi;
                    lA[row][j] = (_Float16)(h - (float)hi);
                }
            }

            #pragma unroll
            for (int kc = 0; kc < 4; ++kc)
                a[kc] = *(const half8*)&lA[col][kc * 32 + quad * 8];
            #pragma unroll
            for (int kc = 0; kc < 4; ++kc)
                #pragma unroll
                for (int nt = 0; nt < 4; ++nt)
                    accA[nt] = __builtin_amdgcn_mfma_f32_16x16x32_f16(a[kc], Wf[nt][kc], accA[nt], 0, 0, 0);
            if (k > 0 && (w == 0 || w == 2)) {
                #pragma unroll
                for (int kc = 0; kc < 4; ++kc)
                    eacc = __builtin_amdgcn_mfma_f32_16x16x32_f16(a[kc], Ef[kc], eacc, 0, 0, 0);
            }

            if (k > 0) {   // cell(B,k-1) rows 2-3
                #pragma unroll
                for (int r = 2; r < 4; ++r) {
                    const int row = 16 + quad * 4 + r;
                    const float gi = fsig_pre(accB[0][r]);
                    const float gf = fsig_pre(accB[1][r]);
                    const float gg = ftanh_pre(accB[2][r]);
                    const float go = fsig_pre(accB[3][r]);
                    c[1][r] = gf * c[1][r] + gi * gg;
                    const float h = go * ftanh_pre(TWO_LOG2E * c[1][r]);
                    const _Float16 hi = (_Float16)h;
                    hA[row][j] = hi;
                    lA[row][j] = (_Float16)(h - (float)hi);
                }
            }

            if (k > 0 && w == 0) {   // x_k(A); k=0 keeps obs-x0 (R4 lesson)
                #pragma unroll
                for (int r = 0; r < 4; ++r)
                    xS[0][quad * 4 + r][col] = (_Float16)ftanh_pre(eacc[r]);
            }
            if (k > 0 && w == 2 && col < 2) {   // rel_{k-1}(A)
                #pragma unroll
                for (int r = 0; r < 4; ++r)
                    out[(base + quad * 4 + r) * (TSTEPS * 2) + (k - 1) * 2 + col] = eacc[r];
            }
            __syncthreads();
        }
        // ================= ODD: gates(B,k) ; x+cell(A,k) =================
        {
            half8 a[4];
            #pragma unroll
            for (int kc = 0; kc < 4; ++kc)
                a[kc] = *(const half8*)&hA[16 + col][kc * 32 + quad * 8];

            {   // finish gates(A,k): x part (xS[0] = obs-x0 at k=0, else wave0's write)
                const half8 xa = *(const half8*)&xS[0][col][quad * 8];
                #pragma unroll
                for (int nt = 0; nt < 4; ++nt)
                    accA[nt] = __builtin_amdgcn_mfma_f32_16x16x32_f16(xa, Wf[nt][4], accA[nt], 0, 0, 0);
            }

            #pragma unroll
            for (int nt = 0; nt < 4; ++nt) {
                f32x4 bv = {bias[nt], bias[nt], bias[nt], bias[nt]};
                accB[nt] = bv;
            }
            f32x4 eacc = {einit, einit, einit, einit};

            #pragma unroll
            for (int kc = 0; kc < 4; ++kc)
                #pragma unroll
                for (int nt = 0; nt < 4; ++nt)
                    accB[nt] = __builtin_amdgcn_mfma_f32_16x16x32_f16(a[kc], Wf[nt][kc], accB[nt], 0, 0, 0);
            if (w == 1 || w == 3) {
                #pragma unroll
                for (int kc = 0; kc < 4; ++kc)
                    eacc = __builtin_amdgcn_mfma_f32_16x16x32_f16(a[kc], Ef[kc], eacc, 0, 0, 0);
            }

            {   // cell(A,k) rows 0-1
                #pragma unroll
                for (int r = 0; r < 2; ++r) {
                    const int row = quad * 4 + r;
                    const float gi = fsig_pre(accA[0][r]);
                    const float gf = fsig_pre(accA[1][r]);
                    const float gg = ftanh_pre(accA[2][r]);
                    const float go = fsig_pre(accA[3][r]);
                    c[0][r] = gf * c[0][r] + gi * gg;
                    const float h = go * ftanh_pre(TWO_LOG2E * c[0][r]);
                    const _Float16 hi = (_Float16)h;
                    hA[row][j] = hi;
                    lA[row][j] = (_Float16)(h - (float)hi);
                }
            }

            #pragma unroll
            for (int kc = 0; kc < 4; ++kc)
                a[kc] = *(const half8*)&lA[16 + col][kc * 32 + quad * 8];
            #pragma unroll
            for (int kc = 0; kc < 4; ++kc)
                #pragma unroll
                for (int nt = 0; nt < 4; ++nt)
                    accB[nt] = __builtin_amdgcn_mfma_f32_16x16x32_f16(a[kc], Wf[nt][kc], accB[nt], 0, 0, 0);
            if (w == 1 || w == 3) {
                #pragma unroll
                for (int kc = 0; kc < 4; ++kc)
                    eacc = __builtin_amdgcn_mfma_f32_16x16x32_f16(a[kc], Ef[kc], eacc, 0, 0, 0);
            }

            {   // cell(A,k) rows 2-3
                #pragma unroll
                for (int r = 2; r < 4; ++r) {
                    const int row = quad * 4 + r;
                    const float gi = fsig_pre(accA[0][r]);
                    const float gf = fsig_pre(accA[1][r]);
                    const float gg = ftanh_pre(accA[2][r]);
                    const float go = fsig_pre(accA[3][r]);
                    c[0][r] = gf * c[0][r] + gi * gg;
                    const float h = go * ftanh_pre(TWO_LOG2E * c[0][r]);
                    const _Float16 hi = (_Float16)h;
                    hA[row][j] = hi;
                    lA[row][j] = (_Float16)(h - (float)hi);
                }
            }

            if (k > 0 && w == 1) {   // x_k(B); k=0 keeps obs-x0
                #pragma unroll
                for (int r = 0; r < 4; ++r)
                    xS[1][quad * 4 + r][col] = (_Float16)ftanh_pre(eacc[r]);
            }
            if (k > 0 && w == 3 && col < 2) {   // rel_{k-1}(B)
                #pragma unroll
                for (int r = 0; r < 4; ++r)
                    out[(base + 16 + quad * 4 + r) * (TSTEPS * 2) + (k - 1) * 2 + col] = eacc[r];
            }
            __syncthreads();
        }
    }

    // ================= epilogue: finish B step 29; rel_29 both tiles =================
    {
        {
            const half8 xb = *(const half8*)&xS[1][col][quad * 8];
            #pragma unroll
            for (int nt = 0; nt < 4; ++nt)
                accB[nt] = __builtin_amdgcn_mfma_f32_16x16x32_f16(xb, Wf[nt][4], accB[nt], 0, 0, 0);
        }
        if (w == 2) {   // rel_29(A) from h_30(A)
            f32x4 eacc = {einit, einit, einit, einit};
            #pragma unroll
            for (int kc = 0; kc < 4; ++kc) {
                const half8 aH = *(const half8*)&hA[col][kc * 32 + quad * 8];
                eacc = __builtin_amdgcn_mfma_f32_16x16x32_f16(aH, Ef[kc], eacc, 0, 0, 0);
            }
            #pragma unroll
            for (int kc = 0; kc < 4; ++kc) {
                const half8 aL = *(const half8*)&lA[col][kc * 32 + quad * 8];
                eacc = __builtin_amdgcn_mfma_f32_16x16x32_f16(aL, Ef[kc], eacc, 0, 0, 0);
            }
            if (col < 2) {
                #pragma unroll
                for (int r = 0; r < 4; ++r)
                    out[(base + quad * 4 + r) * (TSTEPS * 2) + (TSTEPS - 1) * 2 + col] = eacc[r];
            }
        }
        #pragma unroll
        for (int r = 0; r < 4; ++r) {   // cell(B,29) -> h_30(B)
            const int row = 16 + quad * 4 + r;
            const float gi = fsig_pre(accB[0][r]);
            const float gf = fsig_pre(accB[1][r]);
            const float gg = ftanh_pre(accB[2][r]);
            const float go = fsig_pre(accB[3][r]);
            c[1][r] = gf * c[1][r] + gi * gg;
            const float h = go * ftanh_pre(TWO_LOG2E * c[1][r]);
            const _Float16 hi = (_Float16)h;
            hA[row][j] = hi;
            lA[row][j] = (_Float16)(h - (float)hi);
        }
        __syncthreads();
        if (w == 3) {   // rel_29(B) from h_30(B)
            f32x4 eacc = {einit, einit, einit, einit};
            #pragma unroll
            for (int kc = 0; kc < 4; ++kc) {
                const half8 aH = *(const half8*)&hA[16 + col][kc * 32 + quad * 8];
                eacc = __builtin_amdgcn_mfma_f32_16x16x32_f16(aH, Ef[kc], eacc, 0, 0, 0);
            }
            #pragma unroll
            for (int kc = 0; kc < 4; ++kc) {
                const half8 aL = *(const half8*)&lA[16 + col][kc * 32 + quad * 8];
                eacc = __builtin_amdgcn_mfma_f32_16x16x32_f16(aL, Ef[kc], eacc, 0, 0, 0);
            }
            if (col < 2) {
                #pragma unroll
                for (int r = 0; r < 4; ++r)
                    out[(base + 16 + quad * 4 + r) * (TSTEPS * 2) + (TSTEPS - 1) * 2 + col] = eacc[r];
            }
        }
    }
}

extern "C" void kernel_launch(void* const* d_in, const int* in_sizes, int n_in,
                              void* d_out, int out_size, void* d_ws, size_t ws_size,
                              hipStream_t stream) {
    const float* last_obs_rel = (const float*)d_in[1];
    const float* h0    = (const float*)d_in[2];
    const float* c0    = (const float*)d_in[3];
    const float* W_sp  = (const float*)d_in[4];
    const float* b_sp  = (const float*)d_in[5];
    const float* W_ih  = (const float*)d_in[6];
    const float* b_ih  = (const float*)d_in[7];
    const float* W_hh  = (const float*)d_in[8];
    const float* b_hh  = (const float*)d_in[9];
    const float* W_out = (const float*)d_in[10];
    const float* b_out = (const float*)d_in[11];
    float* out = (float*)d_out;

    const int batch = in_sizes[2] / 128;   // 65536
    lstm30_kernel<<<dim3(batch / 32), dim3(512), 0, stream>>>(
        last_obs_rel, h0, c0, W_sp, b_sp, W_ih, b_ih, W_hh, b_hh, W_out, b_out, out);
}

// Round 8
// 626.240 us; speedup vs baseline: 1.3895x; 1.1725x over previous
//
#include <hip/hip_runtime.h>

#define TSTEPS 30
#define KP2 136   // 128 h + 8 pad halfs; gate frags read only k<128

#define LOG2E     1.44269504f
#define TWO_LOG2E 2.88539008f

typedef _Float16 half8 __attribute__((ext_vector_type(8)));
typedef float f32x4 __attribute__((ext_vector_type(4)));

__device__ __forceinline__ float fexp2(float x) { return __builtin_amdgcn_exp2f(x); }
__device__ __forceinline__ float frcp(float x)  { return __builtin_amdgcn_rcpf(x); }
__device__ __forceinline__ float fsig_pre(float x)  { return frcp(1.0f + fexp2(-x)); }
__device__ __forceinline__ float ftanh_pre(float x) { return 1.0f - 2.0f * frcp(1.0f + fexp2(x)); }

// Block = 8 waves, 32 rows as two pipelined 16-row tiles (A=0..15, B=16..31), 2 barriers/step.
// R8: gate path and x path (eaccM) read h_hi ONLY (f16 quant error through the saturating
// gates is ~4e-5/step — under the output threshold); the rel output path (eaccW, waves 2/3)
// keeps the hi+lo compensated read so out[] precision is unchanged. Halves gate MFMA volume.
__global__ __launch_bounds__(512, 2)
void lstm30_kernel(const float* __restrict__ last_obs_rel,
                   const float* __restrict__ h0,
                   const float* __restrict__ c0,
                   const float* __restrict__ W_sp,
                   const float* __restrict__ b_sp,
                   const float* __restrict__ W_ih,
                   const float* __restrict__ b_ih,
                   const float* __restrict__ W_hh,
                   const float* __restrict__ b_hh,
                   const float* __restrict__ W_out,
                   const float* __restrict__ b_out,
                   float* __restrict__ out)
{
    __shared__ _Float16 hA[32][KP2];
    __shared__ _Float16 lA[32][KP2];
    __shared__ _Float16 xS[2][16][32];   // x per tile: e0..15 = x vals, e16..31 = 0

    const int tid  = threadIdx.x;
    const int w    = tid >> 6;
    const int L    = tid & 63;
    const int quad = L >> 4;
    const int col  = L & 15;
    const int base = blockIdx.x << 5;

    // ---- gate B fragments: W'[k][G], G = nt*128 + 16w + col, pre-scaled ----
    half8 Wf[4][5];
    float bias[4];
    #pragma unroll
    for (int nt = 0; nt < 4; ++nt) {
        const int G = nt * 128 + w * 16 + col;
        const float gsc = (nt == 2) ? TWO_LOG2E : LOG2E;
        bias[nt] = (b_ih[G] + b_hh[G]) * gsc;
        #pragma unroll
        for (int kc = 0; kc < 5; ++kc) {
            const int k0 = kc * 32 + quad * 8;
            float v[8];
            if (k0 < 128) {
                const float4 a = *(const float4*)&W_hh[G * 128 + k0];
                const float4 b = *(const float4*)&W_hh[G * 128 + k0 + 4];
                v[0]=a.x; v[1]=a.y; v[2]=a.z; v[3]=a.w;
                v[4]=b.x; v[5]=b.y; v[6]=b.z; v[7]=b.w;
            } else if (k0 < 144) {
                const float4 a = *(const float4*)&W_ih[G * 16 + (k0 - 128)];
                const float4 b = *(const float4*)&W_ih[G * 16 + (k0 - 128) + 4];
                v[0]=a.x; v[1]=a.y; v[2]=a.z; v[3]=a.w;
                v[4]=b.x; v[5]=b.y; v[6]=b.z; v[7]=b.w;
            } else {
                #pragma unroll
                for (int jj = 0; jj < 8; ++jj) v[jj] = 0.0f;
            }
            half8 hh;
            #pragma unroll
            for (int jj = 0; jj < 8; ++jj) hh[jj] = (_Float16)(v[jj] * gsc);
            Wf[nt][kc] = hh;
        }
    }

    const float ws0 = W_sp[col * 2 + 0];
    const float ws1 = W_sp[col * 2 + 1];
    const float bs  = b_sp[col];
    const float bo0 = b_out[0], bo1 = b_out[1];

    // ---- ONE extra-column fragment set per wave: M-cols (w0/w1) or Wout-cols (w2/w3) ----
    half8 Ef[4];
    float einit = 0.0f;
    if (w < 4) {
        const bool isM = (w < 2);
        #pragma unroll
        for (int kc = 0; kc < 4; ++kc) {
            const int k0 = kc * 32 + quad * 8;
            const float4 a0 = *(const float4*)&W_out[k0];
            const float4 a1 = *(const float4*)&W_out[k0 + 4];
            const float4 b0 = *(const float4*)&W_out[128 + k0];
            const float4 b1 = *(const float4*)&W_out[128 + k0 + 4];
            float r0[8] = {a0.x,a0.y,a0.z,a0.w,a1.x,a1.y,a1.z,a1.w};
            float r1[8] = {b0.x,b0.y,b0.z,b0.w,b1.x,b1.y,b1.z,b1.w};
            half8 he;
            #pragma unroll
            for (int jj = 0; jj < 8; ++jj)
                he[jj] = isM ? (_Float16)((ws0 * r0[jj] + ws1 * r1[jj]) * TWO_LOG2E)
                             : (_Float16)((col == 0) ? r0[jj] : (col == 1) ? r1[jj] : 0.0f);
            Ef[kc] = he;
        }
        einit = isM ? (ws0 * bo0 + ws1 * bo1 + bs) * TWO_LOG2E
                    : ((col == 0) ? bo0 : (col == 1) ? bo1 : 0.0f);
    }

    float c[2][4];
    #pragma unroll
    for (int tt = 0; tt < 2; ++tt)
        #pragma unroll
        for (int r = 0; r < 4; ++r)
            c[tt][r] = c0[(base + tt * 16 + quad * 4 + r) * 128 + w * 16 + col];

    // ---- prologue ----
    for (int idx = tid; idx < 32 * 128; idx += 512) {
        const int r = idx >> 7, k = idx & 127;
        const float v = h0[base * 128 + idx];
        const _Float16 hi = (_Float16)v;
        hA[r][k] = hi;
        lA[r][k] = (_Float16)(v - (float)hi);
    }
    {
        const int rr = tid >> 4;
        const float p0 = last_obs_rel[(base + rr) * 2 + 0];
        const float p1 = last_obs_rel[(base + rr) * 2 + 1];
        xS[rr >> 4][rr & 15][col] = (_Float16)ftanh_pre(TWO_LOG2E * (ws0 * p0 + ws1 * p1 + bs));
    }
    for (int flat = tid; flat < 2 * 16 * 16; flat += 512) {
        const int T = flat >> 8, row = (flat >> 4) & 15;
        xS[T][row][16 + (flat & 15)] = (_Float16)0.0f;
    }
    __syncthreads();

    const int j = w * 16 + col;
    f32x4 accA[4], accB[4];

    for (int k = 0; k < TSTEPS; ++k) {
        // ================= EVEN: gates(A,k) hi-only ; x+cell(B,k-1) =================
        {
            half8 a[4];
            #pragma unroll
            for (int kc = 0; kc < 4; ++kc)
                a[kc] = *(const half8*)&hA[col][kc * 32 + quad * 8];

            if (k > 0) {   // finish gates(B,k-1): x part
                const half8 xb = *(const half8*)&xS[1][col][quad * 8];
                #pragma unroll
                for (int nt = 0; nt < 4; ++nt)
                    accB[nt] = __builtin_amdgcn_mfma_f32_16x16x32_f16(xb, Wf[nt][4], accB[nt], 0, 0, 0);
            }

            #pragma unroll
            for (int nt = 0; nt < 4; ++nt) {
                f32x4 bv = {bias[nt], bias[nt], bias[nt], bias[nt]};
                accA[nt] = bv;
            }
            f32x4 eacc = {einit, einit, einit, einit};

            #pragma unroll
            for (int kc = 0; kc < 4; ++kc)
                #pragma unroll
                for (int nt = 0; nt < 4; ++nt)
                    accA[nt] = __builtin_amdgcn_mfma_f32_16x16x32_f16(a[kc], Wf[nt][kc], accA[nt], 0, 0, 0);

            if (k > 0) {   // cell(B,k-1) rows 0-1 — VALU overlaps MFMA drain
                #pragma unroll
                for (int r = 0; r < 2; ++r) {
                    const int row = 16 + quad * 4 + r;
                    const float gi = fsig_pre(accB[0][r]);
                    const float gf = fsig_pre(accB[1][r]);
                    const float gg = ftanh_pre(accB[2][r]);
                    const float go = fsig_pre(accB[3][r]);
                    c[1][r] = gf * c[1][r] + gi * gg;
                    const float h = go * ftanh_pre(TWO_LOG2E * c[1][r]);
                    const _Float16 hi = (_Float16)h;
                    hA[row][j] = hi;
                    lA[row][j] = (_Float16)(h - (float)hi);
                }
            }

            if (k > 0 && w == 0) {        // x-path: hi only
                #pragma unroll
                for (int kc = 0; kc < 4; ++kc)
                    eacc = __builtin_amdgcn_mfma_f32_16x16x32_f16(a[kc], Ef[kc], eacc, 0, 0, 0);
            }
            if (k > 0 && w == 2) {        // rel-path: hi + lo (output precision)
                #pragma unroll
                for (int kc = 0; kc < 4; ++kc)
                    eacc = __builtin_amdgcn_mfma_f32_16x16x32_f16(a[kc], Ef[kc], eacc, 0, 0, 0);
                half8 aL[4];
                #pragma unroll
                for (int kc = 0; kc < 4; ++kc)
                    aL[kc] = *(const half8*)&lA[col][kc * 32 + quad * 8];
                #pragma unroll
                for (int kc = 0; kc < 4; ++kc)
                    eacc = __builtin_amdgcn_mfma_f32_16x16x32_f16(aL[kc], Ef[kc], eacc, 0, 0, 0);
            }

            if (k > 0) {   // cell(B,k-1) rows 2-3
                #pragma unroll
                for (int r = 2; r < 4; ++r) {
                    const int row = 16 + quad * 4 + r;
                    const float gi = fsig_pre(accB[0][r]);
                    const float gf = fsig_pre(accB[1][r]);
                    const float gg = ftanh_pre(accB[2][r]);
                    const float go = fsig_pre(accB[3][r]);
                    c[1][r] = gf * c[1][r] + gi * gg;
                    const float h = go * ftanh_pre(TWO_LOG2E * c[1][r]);
                    const _Float16 hi = (_Float16)h;
                    hA[row][j] = hi;
                    lA[row][j] = (_Float16)(h - (float)hi);
                }
            }

            if (k > 0 && w == 0) {   // x_k(A); k=0 keeps obs-x0 (R4 lesson)
                #pragma unroll
                for (int r = 0; r < 4; ++r)
                    xS[0][quad * 4 + r][col] = (_Float16)ftanh_pre(eacc[r]);
            }
            if (k > 0 && w == 2 && col < 2) {   // rel_{k-1}(A)
                #pragma unroll
                for (int r = 0; r < 4; ++r)
                    out[(base + quad * 4 + r) * (TSTEPS * 2) + (k - 1) * 2 + col] = eacc[r];
            }
            __syncthreads();
        }
        // ================= ODD: gates(B,k) hi-only ; x+cell(A,k) =================
        {
            half8 a[4];
            #pragma unroll
            for (int kc = 0; kc < 4; ++kc)
                a[kc] = *(const half8*)&hA[16 + col][kc * 32 + quad * 8];

            {   // finish gates(A,k): x part (xS[0] = obs-x0 at k=0, else wave0's write)
                const half8 xa = *(const half8*)&xS[0][col][quad * 8];
                #pragma unroll
                for (int nt = 0; nt < 4; ++nt)
                    accA[nt] = __builtin_amdgcn_mfma_f32_16x16x32_f16(xa, Wf[nt][4], accA[nt], 0, 0, 0);
            }

            #pragma unroll
            for (int nt = 0; nt < 4; ++nt) {
                f32x4 bv = {bias[nt], bias[nt], bias[nt], bias[nt]};
                accB[nt] = bv;
            }
            f32x4 eacc = {einit, einit, einit, einit};

            #pragma unroll
            for (int kc = 0; kc < 4; ++kc)
                #pragma unroll
                for (int nt = 0; nt < 4; ++nt)
                    accB[nt] = __builtin_amdgcn_mfma_f32_16x16x32_f16(a[kc], Wf[nt][kc], accB[nt], 0, 0, 0);

            {   // cell(A,k) rows 0-1
                #pragma unroll
                for (int r = 0; r < 2; ++r) {
                    const int row = quad * 4 + r;
                    const float gi = fsig_pre(accA[0][r]);
                    const float gf = fsig_pre(accA[1][r]);
                    const float gg = ftanh_pre(accA[2][r]);
                    const float go = fsig_pre(accA[3][r]);
                    c[0][r] = gf * c[0][r] + gi * gg;
                    const float h = go * ftanh_pre(TWO_LOG2E * c[0][r]);
                    const _Float16 hi = (_Float16)h;
                    hA[row][j] = hi;
                    lA[row][j] = (_Float16)(h - (float)hi);
                }
            }

            if (w == 1) {        // x-path: hi only
                #pragma unroll
                for (int kc = 0; kc < 4; ++kc)
                    eacc = __builtin_amdgcn_mfma_f32_16x16x32_f16(a[kc], Ef[kc], eacc, 0, 0, 0);
            }
            if (w == 3) {        // rel-path: hi + lo
                #pragma unroll
                for (int kc = 0; kc < 4; ++kc)
                    eacc = __builtin_amdgcn_mfma_f32_16x16x32_f16(a[kc], Ef[kc], eacc, 0, 0, 0);
                half8 aL[4];
                #pragma unroll
                for (int kc = 0; kc < 4; ++kc)
                    aL[kc] = *(const half8*)&lA[16 + col][kc * 32 + quad * 8];
                #pragma unroll
                for (int kc = 0; kc < 4; ++kc)
                    eacc = __builtin_amdgcn_mfma_f32_16x16x32_f16(aL[kc], Ef[kc], eacc, 0, 0, 0);
            }

            {   // cell(A,k) rows 2-3
                #pragma unroll
                for (int r = 2; r < 4; ++r) {
                    const int row = quad * 4 + r;
                    const float gi = fsig_pre(accA[0][r]);
                    const float gf = fsig_pre(accA[1][r]);
                    const float gg = ftanh_pre(accA[2][r]);
                    const float go = fsig_pre(accA[3][r]);
                    c[0][r] = gf * c[0][r] + gi * gg;
                    const float h = go * ftanh_pre(TWO_LOG2E * c[0][r]);
                    const _Float16 hi = (_Float16)h;
                    hA[row][j] = hi;
                    lA[row][j] = (_Float16)(h - (float)hi);
                }
            }

            if (k > 0 && w == 1) {   // x_k(B); k=0 keeps obs-x0
                #pragma unroll
                for (int r = 0; r < 4; ++r)
                    xS[1][quad * 4 + r][col] = (_Float16)ftanh_pre(eacc[r]);
            }
            if (k > 0 && w == 3 && col < 2) {   // rel_{k-1}(B)
                #pragma unroll
                for (int r = 0; r < 4; ++r)
                    out[(base + 16 + quad * 4 + r) * (TSTEPS * 2) + (k - 1) * 2 + col] = eacc[r];
            }
            __syncthreads();
        }
    }

    // ================= epilogue: finish B step 29; rel_29 both tiles (hi+lo) =================
    {
        {
            const half8 xb = *(const half8*)&xS[1][col][quad * 8];
            #pragma unroll
            for (int nt = 0; nt < 4; ++nt)
                accB[nt] = __builtin_amdgcn_mfma_f32_16x16x32_f16(xb, Wf[nt][4], accB[nt], 0, 0, 0);
        }
        if (w == 2) {   // rel_29(A) from h_30(A)
            f32x4 eacc = {einit, einit, einit, einit};
            #pragma unroll
            for (int kc = 0; kc < 4; ++kc) {
                const half8 aH = *(const half8*)&hA[col][kc * 32 + quad * 8];
                eacc = __builtin_amdgcn_mfma_f32_16x16x32_f16(aH, Ef[kc], eacc, 0, 0, 0);
            }
            #pragma unroll
            for (int kc = 0; kc < 4; ++kc) {
                const half8 aL = *(const half8*)&lA[col][kc * 32 + quad * 8];
                eacc = __builtin_amdgcn_mfma_f32_16x16x32_f16(aL, Ef[kc], eacc, 0, 0, 0);
            }
            if (col < 2) {
                #pragma unroll
                for (int r = 0; r < 4; ++r)
                    out[(base + quad * 4 + r) * (TSTEPS * 2) + (TSTEPS - 1) * 2 + col] = eacc[r];
            }
        }
        #pragma unroll
        for (int r = 0; r < 4; ++r) {   // cell(B,29) -> h_30(B)
            const int row = 16 + quad * 4 + r;
            const float gi = fsig_pre(accB[0][r]);
            const float gf = fsig_pre(accB[1][r]);
            const float gg = ftanh_pre(accB[2][r]);
            const float go = fsig_pre(accB[3][r]);
            c[1][r] = gf * c[1][r] + gi * gg;
            const float h = go * ftanh_pre(TWO_LOG2E * c[1][r]);
            const _Float16 hi = (_Float16)h;
            hA[row][j] = hi;
            lA[row][j] = (_Float16)(h - (float)hi);
        }
        __syncthreads();
        if (w == 3) {   // rel_29(B) from h_30(B)
            f32x4 eacc = {einit, einit, einit, einit};
            #pragma unroll
            for (int kc = 0; kc < 4; ++kc) {
                const half8 aH = *(const half8*)&hA[16 + col][kc * 32 + quad * 8];
                eacc = __builtin_amdgcn_mfma_f32_16x16x32_f16(aH, Ef[kc], eacc, 0, 0, 0);
            }
            #pragma unroll
            for (int kc = 0; kc < 4; ++kc) {
                const half8 aL = *(const half8*)&lA[16 + col][kc * 32 + quad * 8];
                eacc = __builtin_amdgcn_mfma_f32_16x16x32_f16(aL, Ef[kc], eacc, 0, 0, 0);
            }
            if (col < 2) {
                #pragma unroll
                for (int r = 0; r < 4; ++r)
                    out[(base + 16 + quad * 4 + r) * (TSTEPS * 2) + (TSTEPS - 1) * 2 + col] = eacc[r];
            }
        }
    }
}

extern "C" void kernel_launch(void* const* d_in, const int* in_sizes, int n_in,
                              void* d_out, int out_size, void* d_ws, size_t ws_size,
                              hipStream_t stream) {
    const float* last_obs_rel = (const float*)d_in[1];
    const float* h0    = (const float*)d_in[2];
    const float* c0    = (const float*)d_in[3];
    const float* W_sp  = (const float*)d_in[4];
    const float* b_sp  = (const float*)d_in[5];
    const float* W_ih  = (const float*)d_in[6];
    const float* b_ih  = (const float*)d_in[7];
    const float* W_hh  = (const float*)d_in[8];
    const float* b_hh  = (const float*)d_in[9];
    const float* W_out = (const float*)d_in[10];
    const float* b_out = (const float*)d_in[11];
    float* out = (float*)d_out;

    const int batch = in_sizes[2] / 128;   // 65536
    lstm30_kernel<<<dim3(batch / 32), dim3(512), 0, stream>>>(
        last_obs_rel, h0, c0, W_sp, b_sp, W_ih, b_ih, W_hh, b_hh, W_out, b_out, out);
}